// Round 13
// baseline (500.342 us; speedup 1.0000x reference)
//
#include <hip/hip_runtime.h>

#define D 64

typedef __attribute__((ext_vector_type(8))) short bf16x8;
typedef __attribute__((ext_vector_type(4))) float f32x4;

// f32 -> bf16 round-to-nearest-even (sign-safe; data has no NaN/Inf)
static __device__ __forceinline__ unsigned short f2bf(float x) {
    union { float f; unsigned int u; } v; v.f = x;
    const unsigned int r = (v.u + 0x7fffu + ((v.u >> 16) & 1u)) >> 16;
    return (unsigned short)r;
}
static __device__ __forceinline__ float bf2f(unsigned short u) {
    union { unsigned int i; float f; } v; v.i = ((unsigned int)u) << 16; return v.f;
}
static __device__ __forceinline__ bf16x8 pack8(const f32x4 a, const f32x4 b) {
    union { bf16x8 v; unsigned int u[4]; } p;
    p.u[0] = (unsigned)f2bf(a.x) | ((unsigned)f2bf(a.y) << 16);
    p.u[1] = (unsigned)f2bf(a.z) | ((unsigned)f2bf(a.w) << 16);
    p.u[2] = (unsigned)f2bf(b.x) | ((unsigned)f2bf(b.y) << 16);
    p.u[3] = (unsigned)f2bf(b.z) | ((unsigned)f2bf(b.w) << 16);
    return p.v;
}

// ---------------- K1: per-node edge-update partials (bf16) + attention projections ----------------
__global__ __launch_bounds__(256)
void premix_kernel(const float* __restrict__ nodes, const float* __restrict__ We,
                   const float* __restrict__ Wa,
                   unsigned short* __restrict__ PSb, unsigned short* __restrict__ PRb,
                   float* __restrict__ ps, float* __restrict__ pr, int N)
{
    __shared__ float sWS[64][68];
    __shared__ float sWR[64][68];
    __shared__ float sX[64][68];
    __shared__ float sWa[128];

    const int t = threadIdx.x;
    const int o = t & 63;
    const int k0 = (t >> 6) * 16;
#pragma unroll
    for (int k = 0; k < 16; ++k) {
        sWS[k0 + k][o] = We[(size_t)o * 192 + 64 + k0 + k];
        sWR[k0 + k][o] = We[(size_t)o * 192 + 128 + k0 + k];
    }
    if (t < 128) sWa[t] = Wa[t];

    const int nb = blockIdx.x * 64;
    const int ln = t & 63;
    const int gn = min(nb + ln, N - 1);
    {
        const float* src = nodes + (size_t)gn * D + k0;
        const f32x4 x0 = *(const f32x4*)(src + 0);
        const f32x4 x1 = *(const f32x4*)(src + 4);
        const f32x4 x2 = *(const f32x4*)(src + 8);
        const f32x4 x3 = *(const f32x4*)(src + 12);
        sX[k0 + 0][ln] = x0.x;  sX[k0 + 1][ln] = x0.y;
        sX[k0 + 2][ln] = x0.z;  sX[k0 + 3][ln] = x0.w;
        sX[k0 + 4][ln] = x1.x;  sX[k0 + 5][ln] = x1.y;
        sX[k0 + 6][ln] = x1.z;  sX[k0 + 7][ln] = x1.w;
        sX[k0 + 8][ln] = x2.x;  sX[k0 + 9][ln] = x2.y;
        sX[k0 + 10][ln] = x2.z; sX[k0 + 11][ln] = x2.w;
        sX[k0 + 12][ln] = x3.x; sX[k0 + 13][ln] = x3.y;
        sX[k0 + 14][ln] = x3.z; sX[k0 + 15][ln] = x3.w;
    }
    __syncthreads();

    const int o0 = (t & 15) * 4;
    const int rc = (t >> 4) * 4;
    float as[4][4] = {{0.f,0.f,0.f,0.f},{0.f,0.f,0.f,0.f},{0.f,0.f,0.f,0.f},{0.f,0.f,0.f,0.f}};
    float ar[4][4] = {{0.f,0.f,0.f,0.f},{0.f,0.f,0.f,0.f},{0.f,0.f,0.f,0.f},{0.f,0.f,0.f,0.f}};

#pragma unroll 8
    for (int ci = 0; ci < 64; ++ci) {
        const f32x4 xv = *(const f32x4*)&sX[ci][rc];
        const f32x4 ws = *(const f32x4*)&sWS[ci][o0];
        const f32x4 wr = *(const f32x4*)&sWR[ci][o0];
        as[0][0] += xv.x * ws.x; as[0][1] += xv.x * ws.y; as[0][2] += xv.x * ws.z; as[0][3] += xv.x * ws.w;
        as[1][0] += xv.y * ws.x; as[1][1] += xv.y * ws.y; as[1][2] += xv.y * ws.z; as[1][3] += xv.y * ws.w;
        as[2][0] += xv.z * ws.x; as[2][1] += xv.z * ws.y; as[2][2] += xv.z * ws.z; as[2][3] += xv.z * ws.w;
        as[3][0] += xv.w * ws.x; as[3][1] += xv.w * ws.y; as[3][2] += xv.w * ws.z; as[3][3] += xv.w * ws.w;
        ar[0][0] += xv.x * wr.x; ar[0][1] += xv.x * wr.y; ar[0][2] += xv.x * wr.z; ar[0][3] += xv.x * wr.w;
        ar[1][0] += xv.y * wr.x; ar[1][1] += xv.y * wr.y; ar[1][2] += xv.y * wr.z; ar[1][3] += xv.y * wr.w;
        ar[2][0] += xv.z * wr.x; ar[2][1] += xv.z * wr.y; ar[2][2] += xv.z * wr.z; ar[2][3] += xv.z * wr.w;
        ar[3][0] += xv.w * wr.x; ar[3][1] += xv.w * wr.y; ar[3][2] += xv.w * wr.z; ar[3][3] += xv.w * wr.w;
    }

#pragma unroll
    for (int j = 0; j < 4; ++j) {
        const int n = nb + rc + j;
        if (n < N) {
            ushort4 vs, vr;
            vs.x = f2bf(as[j][0]); vs.y = f2bf(as[j][1]); vs.z = f2bf(as[j][2]); vs.w = f2bf(as[j][3]);
            vr.x = f2bf(ar[j][0]); vr.y = f2bf(ar[j][1]); vr.z = f2bf(ar[j][2]); vr.w = f2bf(ar[j][3]);
            *(ushort4*)&PSb[(size_t)n * D + o0] = vs;
            *(ushort4*)&PRb[(size_t)n * D + o0] = vr;
        }
    }

    if (t < 64 && nb + t < N) {
        float p1 = 0.f, p2 = 0.f;
#pragma unroll 8
        for (int k = 0; k < 64; ++k) {
            const float x = sX[k][t];
            p1 += x * sWa[k];
            p2 += x * sWa[64 + k];
        }
        ps[nb + t] = p1;
        pr[nb + t] = p2;
    }
}

// ---------------- K2: per-edge exp(logit) + denom + degree histograms + SLOTS ----------------
__global__ __launch_bounds__(256)
void edge_logit_kernel(const int* __restrict__ snd, const int* __restrict__ rcv,
                       const float* __restrict__ ps, const float* __restrict__ pr,
                       const float* __restrict__ ba, float* __restrict__ elog,
                       float* __restrict__ denom, int* __restrict__ deg_out,
                       int* __restrict__ deg_in, int* __restrict__ slot_out,
                       int* __restrict__ slot_in, int E)
{
    const float bav = ba[0];
    const int stride = gridDim.x * blockDim.x;
    for (int e = blockIdx.x * blockDim.x + threadIdx.x; e < E; e += stride) {
        const int s = snd[e], r = rcv[e];
        const float ex = __expf(ps[s] + pr[r] + bav);
        elog[e] = ex;
        atomicAdd(&denom[r], ex);
        slot_out[e] = atomicAdd(&deg_out[s], 1);
        slot_in[e]  = atomicAdd(&deg_in[r], 1);
    }
}

// ---------------- K3: exclusive prefix scan of degree arrays (int4-vectorized) ----------------
__global__ __launch_bounds__(1024)
void scan_kernel(const int* __restrict__ deg_out, int* __restrict__ off_out,
                 const int* __restrict__ deg_in, int* __restrict__ off_in, int N)
{
    const int* deg = (blockIdx.x == 0) ? deg_out : deg_in;
    int* off       = (blockIdx.x == 0) ? off_out : off_in;
    __shared__ int part[1024];
    const int t = threadIdx.x;
    const int CH = (((N + 1023) / 1024) + 3) & ~3;
    const int c0 = t * CH;
    int s = 0;
    if (c0 + CH <= N) {
#pragma unroll 4
        for (int k = 0; k < CH; k += 4) {
            const int4 v = *(const int4*)&deg[c0 + k];
            s += v.x + v.y + v.z + v.w;
        }
    } else {
        for (int k = 0; k < CH; ++k) {
            const int i = c0 + k;
            if (i < N) s += deg[i];
        }
    }
    part[t] = s;
    __syncthreads();
    for (int d = 1; d < 1024; d <<= 1) {
        int v = 0;
        if (t >= d) v = part[t - d];
        __syncthreads();
        part[t] += v;
        __syncthreads();
    }
    int run = (t == 0) ? 0 : part[t - 1];
    if (c0 + CH <= N) {
#pragma unroll 4
        for (int k = 0; k < CH; k += 4) {
            const int4 v = *(const int4*)&deg[c0 + k];
            int4 w;
            w.x = run; w.y = run + v.x; w.z = w.y + v.y; w.w = w.z + v.z;
            *(int4*)&off[c0 + k] = w;
            run = w.w + v.w;
        }
    } else {
        for (int k = 0; k < CH; ++k) {
            const int i = c0 + k;
            if (i < N) { off[i] = run; run += deg[i]; }
        }
    }
    if (t == 1023) off[N] = part[1023];
}

// ---------------- K4: edge update — atomic-free, pipelined, LDS-free (+optional bf16 shadow) ----------------
template <bool SHADOW>
__global__ __launch_bounds__(256)
void edge_mix_kernel(const float* __restrict__ edges, const int* __restrict__ snd,
                     const int* __restrict__ rcv, const float* __restrict__ We,
                     const float* __restrict__ be,
                     const unsigned short* __restrict__ PSb,
                     const unsigned short* __restrict__ PRb,
                     const float* __restrict__ elog, const float* __restrict__ denom,
                     const int* __restrict__ off_out, const int* __restrict__ off_in,
                     const int* __restrict__ slot_out, const int* __restrict__ slot_in,
                     int* __restrict__ idx_out, int* __restrict__ idx_in,
                     float* __restrict__ w_out, unsigned short* __restrict__ wb, int E)
{
    const int t   = threadIdx.x;
    const int w   = t >> 6;
    const int l   = t & 63;
    const int r16 = l & 15;
    const int kb  = l >> 4;          // 0..3
    const int lanePos = w * 16 + r16;
    const int o0 = kb * 4;

    // A-operand (WeE rows) in registers, once per block
    bf16x8 aw[4][2];
#pragma unroll
    for (int n = 0; n < 4; ++n) {
#pragma unroll
        for (int kt = 0; kt < 2; ++kt) {
            const float* src = We + (size_t)(n * 16 + r16) * 192 + kt * 32 + kb * 8;
            aw[n][kt] = pack8(*(const f32x4*)(src), *(const f32x4*)(src + 4));
        }
    }
    f32x4 bev[4];
#pragma unroll
    for (int n = 0; n < 4; ++n) bev[n] = *(const f32x4*)&be[n * 16 + o0];

    const int nt = (E + 63) >> 6;
    int tile = blockIdx.x;

    // pipeline "next" registers
    int eN = 0, sN = 0, rN = 0, slN = 0, baseN = 0;
    float elN = 0.f;
    f32x4 exN0, exN1, exN2, exN3;
    if (tile < nt) {
        eN = tile * 64 + lanePos;
        const int ec = min(eN, E - 1);
        sN = snd[ec]; rN = rcv[ec]; elN = elog[ec];
        const float* src = edges + (size_t)ec * D + kb * 8;
        exN0 = *(const f32x4*)(src);      exN1 = *(const f32x4*)(src + 4);
        exN2 = *(const f32x4*)(src + 32); exN3 = *(const f32x4*)(src + 36);
        if (kb == 0)      { slN = slot_out[ec]; baseN = off_out[sN]; }
        else if (kb == 1) { slN = slot_in[ec];  baseN = off_in[rN]; }
    }

    while (tile < nt) {
        const int e = eN, s = sN, r = rN, sl = slN, base = baseN;
        const float el = elN;
        const f32x4 x0 = exN0, x1 = exN1, x2 = exN2, x3 = exN3;

        // 1) issue current-tile gathers EARLY
        const float dn = denom[r];
        const unsigned short* psr = PSb + (size_t)s * D + o0;
        const unsigned short* prr = PRb + (size_t)r * D + o0;
        ushort4 psv[4], prv[4];
#pragma unroll
        for (int n = 0; n < 4; ++n) {
            psv[n] = *(const ushort4*)(psr + n * 16);
            prv[n] = *(const ushort4*)(prr + n * 16);
        }

        // 2) prefetch next tile (pure loads)
        const int ntile = tile + gridDim.x;
        if (ntile < nt) {
            eN = ntile * 64 + lanePos;
            const int ec = min(eN, E - 1);
            sN = snd[ec]; rN = rcv[ec]; elN = elog[ec];
            const float* src = edges + (size_t)ec * D + kb * 8;
            exN0 = *(const f32x4*)(src);      exN1 = *(const f32x4*)(src + 4);
            exN2 = *(const f32x4*)(src + 32); exN3 = *(const f32x4*)(src + 36);
            if (kb == 0)      { slN = slot_out[ec]; baseN = off_out[sN]; }
            else if (kb == 1) { slN = slot_in[ec];  baseN = off_in[rN]; }
        }

        // 3) pack + MFMA
        const bf16x8 bx0 = pack8(x0, x1);
        const bf16x8 bx1 = pack8(x2, x3);
        f32x4 acc[4] = {{0.f,0.f,0.f,0.f},{0.f,0.f,0.f,0.f},{0.f,0.f,0.f,0.f},{0.f,0.f,0.f,0.f}};
#pragma unroll
        for (int n = 0; n < 4; ++n) {
            acc[n] = __builtin_amdgcn_mfma_f32_16x16x32_bf16(aw[n][0], bx0, acc[n], 0, 0, 0);
            acc[n] = __builtin_amdgcn_mfma_f32_16x16x32_bf16(aw[n][1], bx1, acc[n], 0, 0, 0);
        }

        // 4) epilogue: CSR scatter (pure store) + vectorized w_out (+bf16 shadow)
        if (e < E) {
            if (kb == 0)      idx_out[base + sl] = e;
            else if (kb == 1) idx_in[base + sl] = e;
            const float att = el / dn;
            float* wo = w_out + (size_t)e * D + o0;
            unsigned short* wbo = SHADOW ? (wb + (size_t)e * D + o0) : nullptr;
#pragma unroll
            for (int n = 0; n < 4; ++n) {
                f32x4 wv;
                wv.x = fmaxf(acc[n][0] + bf2f(psv[n].x) + bf2f(prv[n].x) + bev[n].x, 0.f) * att;
                wv.y = fmaxf(acc[n][1] + bf2f(psv[n].y) + bf2f(prv[n].y) + bev[n].y, 0.f) * att;
                wv.z = fmaxf(acc[n][2] + bf2f(psv[n].z) + bf2f(prv[n].z) + bev[n].z, 0.f) * att;
                wv.w = fmaxf(acc[n][3] + bf2f(psv[n].w) + bf2f(prv[n].w) + bev[n].w, 0.f) * att;
                *(f32x4*)(wo + n * 16) = wv;
                if (SHADOW) {
                    ushort4 pb;
                    pb.x = f2bf(wv.x); pb.y = f2bf(wv.y);
                    pb.z = f2bf(wv.z); pb.w = f2bf(wv.w);
                    *(ushort4*)(wbo + n * 16) = pb;
                }
            }
        }
        tile = ntile;
    }
}

// ---------------- K5a: CSR gather aggregation from bf16 shadow (halved gather bytes) ----------------
__global__ __launch_bounds__(256)
void agg_bf16_kernel(const unsigned short* __restrict__ wb,
                     const int* __restrict__ idx_out, const int* __restrict__ off_out,
                     const int* __restrict__ idx_in, const int* __restrict__ off_in,
                     float* __restrict__ out_agg, float* __restrict__ in_agg, int N)
{
    const int lane = threadIdx.x & 63;
    const int wid  = (blockIdx.x * blockDim.x + threadIdx.x) >> 6;
    if (wid >= 2 * N) return;
    const bool is_out = wid < N;
    const int node = is_out ? wid : wid - N;
    const int* __restrict__ idx = is_out ? idx_out : idx_in;
    const int* __restrict__ off = is_out ? off_out : off_in;
    float* __restrict__ dst = is_out ? out_agg : in_agg;

    const int a = off[node], b = off[node + 1];
    float acc = 0.f;
    int j = a;
    for (; j + 7 < b; j += 8) {
        float v = 0.f;
#pragma unroll
        for (int u = 0; u < 8; ++u)
            v += bf2f(wb[(size_t)idx[j + u] * D + lane]);
        acc += v;
    }
    for (; j < b; ++j) acc += bf2f(wb[(size_t)idx[j] * D + lane]);
    dst[(size_t)node * D + lane] = acc;
}

// ---------------- K5b: fallback f32 aggregation (if ws too small for shadow) ----------------
__global__ __launch_bounds__(256)
void agg_kernel(const float* __restrict__ w_edges,
                const int* __restrict__ idx_out, const int* __restrict__ off_out,
                const int* __restrict__ idx_in, const int* __restrict__ off_in,
                float* __restrict__ out_agg, float* __restrict__ in_agg, int N)
{
    const int lane = threadIdx.x & 63;
    const int wid  = (blockIdx.x * blockDim.x + threadIdx.x) >> 6;
    if (wid >= 2 * N) return;
    const bool is_out = wid < N;
    const int node = is_out ? wid : wid - N;
    const int* __restrict__ idx = is_out ? idx_out : idx_in;
    const int* __restrict__ off = is_out ? off_out : off_in;
    float* __restrict__ dst = is_out ? out_agg : in_agg;

    const int a = off[node], b = off[node + 1];
    float acc = 0.f;
    int j = a;
    for (; j + 3 < b; j += 4) {
        const int e0 = idx[j], e1 = idx[j + 1], e2 = idx[j + 2], e3 = idx[j + 3];
        const float v0 = w_edges[(size_t)e0 * D + lane];
        const float v1 = w_edges[(size_t)e1 * D + lane];
        const float v2 = w_edges[(size_t)e2 * D + lane];
        const float v3 = w_edges[(size_t)e3 * D + lane];
        acc += v0 + v1 + v2 + v3;
    }
    for (; j < b; ++j) acc += w_edges[(size_t)idx[j] * D + lane];
    dst[(size_t)node * D + lane] = acc;
}

// ---------------- K6: node update (3 x K=64 GEMM passes, f32) ----------------
__global__ __launch_bounds__(256)
void node_out_kernel(const float* __restrict__ nodes, const float* __restrict__ oag,
                     const float* __restrict__ iag, const float* __restrict__ Wn,
                     const float* __restrict__ bn, float* __restrict__ out, int N)
{
    __shared__ float sW[64][68];
    __shared__ float sX[64][68];

    const int t = threadIdx.x;
    const int o = t & 63;
    const int k0 = (t >> 6) * 16;
    const int nb = blockIdx.x * 64;
    const int ln = t & 63;
    const int gn = min(nb + ln, N - 1);
    const int o0 = (t & 15) * 4;
    const int rc = (t >> 4) * 4;

    float acc[4][4] = {{0.f,0.f,0.f,0.f},{0.f,0.f,0.f,0.f},{0.f,0.f,0.f,0.f},{0.f,0.f,0.f,0.f}};

#pragma unroll
    for (int g = 0; g < 3; ++g) {
        const float* xbase = (g == 0) ? nodes : ((g == 1) ? oag : iag);
        const float* src = xbase + (size_t)gn * D + k0;
        const f32x4 x0 = *(const f32x4*)(src + 0);
        const f32x4 x1 = *(const f32x4*)(src + 4);
        const f32x4 x2 = *(const f32x4*)(src + 8);
        const f32x4 x3 = *(const f32x4*)(src + 12);
        __syncthreads();
#pragma unroll
        for (int k = 0; k < 16; ++k) {
            sW[k0 + k][o] = Wn[(size_t)o * 192 + g * 64 + k0 + k];
        }
        sX[k0 + 0][ln] = x0.x;  sX[k0 + 1][ln] = x0.y;
        sX[k0 + 2][ln] = x0.z;  sX[k0 + 3][ln] = x0.w;
        sX[k0 + 4][ln] = x1.x;  sX[k0 + 5][ln] = x1.y;
        sX[k0 + 6][ln] = x1.z;  sX[k0 + 7][ln] = x1.w;
        sX[k0 + 8][ln] = x2.x;  sX[k0 + 9][ln] = x2.y;
        sX[k0 + 10][ln] = x2.z; sX[k0 + 11][ln] = x2.w;
        sX[k0 + 12][ln] = x3.x; sX[k0 + 13][ln] = x3.y;
        sX[k0 + 14][ln] = x3.z; sX[k0 + 15][ln] = x3.w;
        __syncthreads();
#pragma unroll 8
        for (int ci = 0; ci < 64; ++ci) {
            const f32x4 xv = *(const f32x4*)&sX[ci][rc];
            const f32x4 wv = *(const f32x4*)&sW[ci][o0];
            acc[0][0] += xv.x * wv.x; acc[0][1] += xv.x * wv.y; acc[0][2] += xv.x * wv.z; acc[0][3] += xv.x * wv.w;
            acc[1][0] += xv.y * wv.x; acc[1][1] += xv.y * wv.y; acc[1][2] += xv.y * wv.z; acc[1][3] += xv.y * wv.w;
            acc[2][0] += xv.z * wv.x; acc[2][1] += xv.z * wv.y; acc[2][2] += xv.z * wv.z; acc[2][3] += xv.z * wv.w;
            acc[3][0] += xv.w * wv.x; acc[3][1] += xv.w * wv.y; acc[3][2] += xv.w * wv.z; acc[3][3] += xv.w * wv.w;
        }
    }

    const f32x4 bnv = *(const f32x4*)&bn[o0];
#pragma unroll
    for (int j = 0; j < 4; ++j) {
        const int n = nb + rc + j;
        if (n < N) {
            f32x4 y;
            y.x = fmaxf(acc[j][0] + bnv.x, 0.f);
            y.y = fmaxf(acc[j][1] + bnv.y, 0.f);
            y.z = fmaxf(acc[j][2] + bnv.z, 0.f);
            y.w = fmaxf(acc[j][3] + bnv.w, 0.f);
            *(f32x4*)&out[(size_t)n * D + o0] = y;
        }
    }
}

extern "C" void kernel_launch(void* const* d_in, const int* in_sizes, int n_in,
                              void* d_out, int out_size, void* d_ws, size_t ws_size,
                              hipStream_t stream) {
    const float* nodes = (const float*)d_in[0];
    const float* edges = (const float*)d_in[1];
    const int*   snd   = (const int*)d_in[2];
    const int*   rcv   = (const int*)d_in[3];
    const float* We    = (const float*)d_in[4];
    const float* be    = (const float*)d_in[5];
    const float* Wn    = (const float*)d_in[6];
    const float* bn    = (const float*)d_in[7];
    const float* Wa    = (const float*)d_in[8];
    const float* ba    = (const float*)d_in[9];

    const int N = in_sizes[0] / D;
    const int E = in_sizes[2];

    float* out_nodes = (float*)d_out;                    // [N, 64]
    float* w_out     = (float*)d_out + (size_t)N * D;    // [E, 64]

    // ws layout (4-byte elems unless noted):
    // zeroed each call: [denom N][deg_out N][deg_in N]
    // [ps N][pr N][off_out N+1][off_in N+1][elog E][idx_out E][idx_in E]
    // [slot_out E][slot_in E][PSb N*64 ushort][PRb N*64 ushort]
    // [out_agg N*64][in_agg N*64] [wb E*64 ushort — only if it fits]
    char* w = (char*)d_ws;
    float* denom    = (float*)w;                 w += (size_t)N * 4;
    int*   deg_out  = (int*)w;                   w += (size_t)N * 4;
    int*   deg_in   = (int*)w;                   w += (size_t)N * 4;
    float* ps       = (float*)w;                 w += (size_t)N * 4;
    float* pr       = (float*)w;                 w += (size_t)N * 4;
    int*   off_out  = (int*)w;                   w += (size_t)(N + 1) * 4;
    int*   off_in   = (int*)w;                   w += (size_t)(N + 1) * 4;
    float* elog     = (float*)w;                 w += (size_t)E * 4;
    int*   idx_out  = (int*)w;                   w += (size_t)E * 4;
    int*   idx_in   = (int*)w;                   w += (size_t)E * 4;
    int*   slot_out = (int*)w;                   w += (size_t)E * 4;
    int*   slot_in  = (int*)w;                   w += (size_t)E * 4;
    unsigned short* PSb = (unsigned short*)w;    w += (size_t)N * D * 2;
    unsigned short* PRb = (unsigned short*)w;    w += (size_t)N * D * 2;
    float* out_agg  = (float*)w;                 w += (size_t)N * D * 4;
    float* in_agg   = (float*)w;                 w += (size_t)N * D * 4;
    unsigned short* wb = (unsigned short*)w;     // optional shadow
    const size_t used = (size_t)(w - (char*)d_ws);
    const bool shadow = (used + (size_t)E * D * 2) <= ws_size;

    hipMemsetAsync(denom, 0, (size_t)3 * N * 4, stream);

    premix_kernel<<<(N + 63) / 64, 256, 0, stream>>>(nodes, We, Wa, PSb, PRb, ps, pr, N);

    edge_logit_kernel<<<1024, 256, 0, stream>>>(snd, rcv, ps, pr, ba, elog,
                                                denom, deg_out, deg_in,
                                                slot_out, slot_in, E);

    scan_kernel<<<2, 1024, 0, stream>>>(deg_out, off_out, deg_in, off_in, N);

    const int nt = (E + 63) / 64;
    const int eblocks = nt < 2048 ? nt : 2048;
    if (shadow) {
        edge_mix_kernel<true><<<eblocks, 256, 0, stream>>>(edges, snd, rcv, We, be,
                                                           PSb, PRb, elog, denom,
                                                           off_out, off_in, slot_out, slot_in,
                                                           idx_out, idx_in, w_out, wb, E);
        agg_bf16_kernel<<<(2 * N + 3) / 4, 256, 0, stream>>>(wb, idx_out, off_out,
                                                             idx_in, off_in, out_agg, in_agg, N);
    } else {
        edge_mix_kernel<false><<<eblocks, 256, 0, stream>>>(edges, snd, rcv, We, be,
                                                            PSb, PRb, elog, denom,
                                                            off_out, off_in, slot_out, slot_in,
                                                            idx_out, idx_in, w_out, nullptr, E);
        agg_kernel<<<(2 * N + 3) / 4, 256, 0, stream>>>(w_out, idx_out, off_out,
                                                        idx_in, off_in, out_agg, in_agg, N);
    }

    node_out_kernel<<<(N + 63) / 64, 256, 0, stream>>>(nodes, out_agg, in_agg,
                                                       Wn, bn, out_nodes, N);
}

// Round 14
// 451.264 us; speedup vs baseline: 1.1088x; 1.1088x over previous
//
#include <hip/hip_runtime.h>

#define D 64

typedef __attribute__((ext_vector_type(8))) short bf16x8;
typedef __attribute__((ext_vector_type(4))) float f32x4;

// f32 -> bf16 round-to-nearest-even (sign-safe; data has no NaN/Inf)
static __device__ __forceinline__ unsigned short f2bf(float x) {
    union { float f; unsigned int u; } v; v.f = x;
    const unsigned int r = (v.u + 0x7fffu + ((v.u >> 16) & 1u)) >> 16;
    return (unsigned short)r;
}
static __device__ __forceinline__ float bf2f(unsigned short u) {
    union { unsigned int i; float f; } v; v.i = ((unsigned int)u) << 16; return v.f;
}
static __device__ __forceinline__ bf16x8 pack8(const f32x4 a, const f32x4 b) {
    union { bf16x8 v; unsigned int u[4]; } p;
    p.u[0] = (unsigned)f2bf(a.x) | ((unsigned)f2bf(a.y) << 16);
    p.u[1] = (unsigned)f2bf(a.z) | ((unsigned)f2bf(a.w) << 16);
    p.u[2] = (unsigned)f2bf(b.x) | ((unsigned)f2bf(b.y) << 16);
    p.u[3] = (unsigned)f2bf(b.z) | ((unsigned)f2bf(b.w) << 16);
    return p.v;
}

// ---------------- K1: per-node edge-update partials (bf16) + attention projections ----------------
__global__ __launch_bounds__(256)
void premix_kernel(const float* __restrict__ nodes, const float* __restrict__ We,
                   const float* __restrict__ Wa,
                   unsigned short* __restrict__ PSb, unsigned short* __restrict__ PRb,
                   float* __restrict__ ps, float* __restrict__ pr, int N)
{
    __shared__ float sWS[64][68];
    __shared__ float sWR[64][68];
    __shared__ float sX[64][68];
    __shared__ float sWa[128];

    const int t = threadIdx.x;
    const int o = t & 63;
    const int k0 = (t >> 6) * 16;
#pragma unroll
    for (int k = 0; k < 16; ++k) {
        sWS[k0 + k][o] = We[(size_t)o * 192 + 64 + k0 + k];
        sWR[k0 + k][o] = We[(size_t)o * 192 + 128 + k0 + k];
    }
    if (t < 128) sWa[t] = Wa[t];

    const int nb = blockIdx.x * 64;
    const int ln = t & 63;
    const int gn = min(nb + ln, N - 1);
    {
        const float* src = nodes + (size_t)gn * D + k0;
        const f32x4 x0 = *(const f32x4*)(src + 0);
        const f32x4 x1 = *(const f32x4*)(src + 4);
        const f32x4 x2 = *(const f32x4*)(src + 8);
        const f32x4 x3 = *(const f32x4*)(src + 12);
        sX[k0 + 0][ln] = x0.x;  sX[k0 + 1][ln] = x0.y;
        sX[k0 + 2][ln] = x0.z;  sX[k0 + 3][ln] = x0.w;
        sX[k0 + 4][ln] = x1.x;  sX[k0 + 5][ln] = x1.y;
        sX[k0 + 6][ln] = x1.z;  sX[k0 + 7][ln] = x1.w;
        sX[k0 + 8][ln] = x2.x;  sX[k0 + 9][ln] = x2.y;
        sX[k0 + 10][ln] = x2.z; sX[k0 + 11][ln] = x2.w;
        sX[k0 + 12][ln] = x3.x; sX[k0 + 13][ln] = x3.y;
        sX[k0 + 14][ln] = x3.z; sX[k0 + 15][ln] = x3.w;
    }
    __syncthreads();

    const int o0 = (t & 15) * 4;
    const int rc = (t >> 4) * 4;
    float as[4][4] = {{0.f,0.f,0.f,0.f},{0.f,0.f,0.f,0.f},{0.f,0.f,0.f,0.f},{0.f,0.f,0.f,0.f}};
    float ar[4][4] = {{0.f,0.f,0.f,0.f},{0.f,0.f,0.f,0.f},{0.f,0.f,0.f,0.f},{0.f,0.f,0.f,0.f}};

#pragma unroll 8
    for (int ci = 0; ci < 64; ++ci) {
        const f32x4 xv = *(const f32x4*)&sX[ci][rc];
        const f32x4 ws = *(const f32x4*)&sWS[ci][o0];
        const f32x4 wr = *(const f32x4*)&sWR[ci][o0];
        as[0][0] += xv.x * ws.x; as[0][1] += xv.x * ws.y; as[0][2] += xv.x * ws.z; as[0][3] += xv.x * ws.w;
        as[1][0] += xv.y * ws.x; as[1][1] += xv.y * ws.y; as[1][2] += xv.y * ws.z; as[1][3] += xv.y * ws.w;
        as[2][0] += xv.z * ws.x; as[2][1] += xv.z * ws.y; as[2][2] += xv.z * ws.z; as[2][3] += xv.z * ws.w;
        as[3][0] += xv.w * ws.x; as[3][1] += xv.w * ws.y; as[3][2] += xv.w * ws.z; as[3][3] += xv.w * ws.w;
        ar[0][0] += xv.x * wr.x; ar[0][1] += xv.x * wr.y; ar[0][2] += xv.x * wr.z; ar[0][3] += xv.x * wr.w;
        ar[1][0] += xv.y * wr.x; ar[1][1] += xv.y * wr.y; ar[1][2] += xv.y * wr.z; ar[1][3] += xv.y * wr.w;
        ar[2][0] += xv.z * wr.x; ar[2][1] += xv.z * wr.y; ar[2][2] += xv.z * wr.z; ar[2][3] += xv.z * wr.w;
        ar[3][0] += xv.w * wr.x; ar[3][1] += xv.w * wr.y; ar[3][2] += xv.w * wr.z; ar[3][3] += xv.w * wr.w;
    }

#pragma unroll
    for (int j = 0; j < 4; ++j) {
        const int n = nb + rc + j;
        if (n < N) {
            ushort4 vs, vr;
            vs.x = f2bf(as[j][0]); vs.y = f2bf(as[j][1]); vs.z = f2bf(as[j][2]); vs.w = f2bf(as[j][3]);
            vr.x = f2bf(ar[j][0]); vr.y = f2bf(ar[j][1]); vr.z = f2bf(ar[j][2]); vr.w = f2bf(ar[j][3]);
            *(ushort4*)&PSb[(size_t)n * D + o0] = vs;
            *(ushort4*)&PRb[(size_t)n * D + o0] = vr;
        }
    }

    if (t < 64 && nb + t < N) {
        float p1 = 0.f, p2 = 0.f;
#pragma unroll 8
        for (int k = 0; k < 64; ++k) {
            const float x = sX[k][t];
            p1 += x * sWa[k];
            p2 += x * sWa[64 + k];
        }
        ps[nb + t] = p1;
        pr[nb + t] = p2;
    }
}

// ---------------- K2: per-edge exp(logit) + denom + degrees + SLOTS (4 edges/thread) ----------------
__global__ __launch_bounds__(256)
void edge_logit_kernel(const int* __restrict__ snd, const int* __restrict__ rcv,
                       const float* __restrict__ ps, const float* __restrict__ pr,
                       const float* __restrict__ ba, float* __restrict__ elog,
                       float* __restrict__ denom, int* __restrict__ deg_out,
                       int* __restrict__ deg_in, int* __restrict__ slot_out,
                       int* __restrict__ slot_in, int E)
{
    const float bav = ba[0];
    const int tid = blockIdx.x * blockDim.x + threadIdx.x;
    const int stride = gridDim.x * blockDim.x;
    const int E4 = E >> 2;
    for (int q = tid; q < E4; q += stride) {
        const int4 s4 = ((const int4*)snd)[q];
        const int4 r4 = ((const int4*)rcv)[q];
        float4 ex;
        ex.x = __expf(ps[s4.x] + pr[r4.x] + bav);
        ex.y = __expf(ps[s4.y] + pr[r4.y] + bav);
        ex.z = __expf(ps[s4.z] + pr[r4.z] + bav);
        ex.w = __expf(ps[s4.w] + pr[r4.w] + bav);
        ((float4*)elog)[q] = ex;
        atomicAdd(&denom[r4.x], ex.x);
        atomicAdd(&denom[r4.y], ex.y);
        atomicAdd(&denom[r4.z], ex.z);
        atomicAdd(&denom[r4.w], ex.w);
        int4 so, si;
        so.x = atomicAdd(&deg_out[s4.x], 1);
        so.y = atomicAdd(&deg_out[s4.y], 1);
        so.z = atomicAdd(&deg_out[s4.z], 1);
        so.w = atomicAdd(&deg_out[s4.w], 1);
        si.x = atomicAdd(&deg_in[r4.x], 1);
        si.y = atomicAdd(&deg_in[r4.y], 1);
        si.z = atomicAdd(&deg_in[r4.z], 1);
        si.w = atomicAdd(&deg_in[r4.w], 1);
        ((int4*)slot_out)[q] = so;
        ((int4*)slot_in)[q]  = si;
    }
    for (int e = E4 * 4 + tid; e < E; e += stride) {
        const int s = snd[e], r = rcv[e];
        const float ex = __expf(ps[s] + pr[r] + bav);
        elog[e] = ex;
        atomicAdd(&denom[r], ex);
        slot_out[e] = atomicAdd(&deg_out[s], 1);
        slot_in[e]  = atomicAdd(&deg_in[r], 1);
    }
}

// ---------------- K3: exclusive prefix scan of degree arrays (int4-vectorized) ----------------
__global__ __launch_bounds__(1024)
void scan_kernel(const int* __restrict__ deg_out, int* __restrict__ off_out,
                 const int* __restrict__ deg_in, int* __restrict__ off_in, int N)
{
    const int* deg = (blockIdx.x == 0) ? deg_out : deg_in;
    int* off       = (blockIdx.x == 0) ? off_out : off_in;
    __shared__ int part[1024];
    const int t = threadIdx.x;
    const int CH = (((N + 1023) / 1024) + 3) & ~3;
    const int c0 = t * CH;
    int s = 0;
    if (c0 + CH <= N) {
#pragma unroll 4
        for (int k = 0; k < CH; k += 4) {
            const int4 v = *(const int4*)&deg[c0 + k];
            s += v.x + v.y + v.z + v.w;
        }
    } else {
        for (int k = 0; k < CH; ++k) {
            const int i = c0 + k;
            if (i < N) s += deg[i];
        }
    }
    part[t] = s;
    __syncthreads();
    for (int d = 1; d < 1024; d <<= 1) {
        int v = 0;
        if (t >= d) v = part[t - d];
        __syncthreads();
        part[t] += v;
        __syncthreads();
    }
    int run = (t == 0) ? 0 : part[t - 1];
    if (c0 + CH <= N) {
#pragma unroll 4
        for (int k = 0; k < CH; k += 4) {
            const int4 v = *(const int4*)&deg[c0 + k];
            int4 w;
            w.x = run; w.y = run + v.x; w.z = w.y + v.y; w.w = w.z + v.z;
            *(int4*)&off[c0 + k] = w;
            run = w.w + v.w;
        }
    } else {
        for (int k = 0; k < CH; ++k) {
            const int i = c0 + k;
            if (i < N) { off[i] = run; run += deg[i]; }
        }
    }
    if (t == 1023) off[N] = part[1023];
}

// ---------------- K4: edge update — atomic-free, pipelined, LDS-free (r12-exact) ----------------
__global__ __launch_bounds__(256)
void edge_mix_kernel(const float* __restrict__ edges, const int* __restrict__ snd,
                     const int* __restrict__ rcv, const float* __restrict__ We,
                     const float* __restrict__ be,
                     const unsigned short* __restrict__ PSb,
                     const unsigned short* __restrict__ PRb,
                     const float* __restrict__ elog, const float* __restrict__ denom,
                     const int* __restrict__ off_out, const int* __restrict__ off_in,
                     const int* __restrict__ slot_out, const int* __restrict__ slot_in,
                     int* __restrict__ idx_out, int* __restrict__ idx_in,
                     float* __restrict__ w_out, int E)
{
    const int t   = threadIdx.x;
    const int w   = t >> 6;
    const int l   = t & 63;
    const int r16 = l & 15;
    const int kb  = l >> 4;          // 0..3
    const int lanePos = w * 16 + r16;
    const int o0 = kb * 4;

    bf16x8 aw[4][2];
#pragma unroll
    for (int n = 0; n < 4; ++n) {
#pragma unroll
        for (int kt = 0; kt < 2; ++kt) {
            const float* src = We + (size_t)(n * 16 + r16) * 192 + kt * 32 + kb * 8;
            aw[n][kt] = pack8(*(const f32x4*)(src), *(const f32x4*)(src + 4));
        }
    }
    f32x4 bev[4];
#pragma unroll
    for (int n = 0; n < 4; ++n) bev[n] = *(const f32x4*)&be[n * 16 + o0];

    const int nt = (E + 63) >> 6;
    int tile = blockIdx.x;

    int eN = 0, sN = 0, rN = 0, slN = 0, baseN = 0;
    float elN = 0.f;
    f32x4 exN0, exN1, exN2, exN3;
    if (tile < nt) {
        eN = tile * 64 + lanePos;
        const int ec = min(eN, E - 1);
        sN = snd[ec]; rN = rcv[ec]; elN = elog[ec];
        const float* src = edges + (size_t)ec * D + kb * 8;
        exN0 = *(const f32x4*)(src);      exN1 = *(const f32x4*)(src + 4);
        exN2 = *(const f32x4*)(src + 32); exN3 = *(const f32x4*)(src + 36);
        if (kb == 0)      { slN = slot_out[ec]; baseN = off_out[sN]; }
        else if (kb == 1) { slN = slot_in[ec];  baseN = off_in[rN]; }
    }

    while (tile < nt) {
        const int e = eN, s = sN, r = rN, sl = slN, base = baseN;
        const float el = elN;
        const f32x4 x0 = exN0, x1 = exN1, x2 = exN2, x3 = exN3;

        const float dn = denom[r];
        const unsigned short* psr = PSb + (size_t)s * D + o0;
        const unsigned short* prr = PRb + (size_t)r * D + o0;
        ushort4 psv[4], prv[4];
#pragma unroll
        for (int n = 0; n < 4; ++n) {
            psv[n] = *(const ushort4*)(psr + n * 16);
            prv[n] = *(const ushort4*)(prr + n * 16);
        }

        const int ntile = tile + gridDim.x;
        if (ntile < nt) {
            eN = ntile * 64 + lanePos;
            const int ec = min(eN, E - 1);
            sN = snd[ec]; rN = rcv[ec]; elN = elog[ec];
            const float* src = edges + (size_t)ec * D + kb * 8;
            exN0 = *(const f32x4*)(src);      exN1 = *(const f32x4*)(src + 4);
            exN2 = *(const f32x4*)(src + 32); exN3 = *(const f32x4*)(src + 36);
            if (kb == 0)      { slN = slot_out[ec]; baseN = off_out[sN]; }
            else if (kb == 1) { slN = slot_in[ec];  baseN = off_in[rN]; }
        }

        const bf16x8 bx0 = pack8(x0, x1);
        const bf16x8 bx1 = pack8(x2, x3);
        f32x4 acc[4] = {{0.f,0.f,0.f,0.f},{0.f,0.f,0.f,0.f},{0.f,0.f,0.f,0.f},{0.f,0.f,0.f,0.f}};
#pragma unroll
        for (int n = 0; n < 4; ++n) {
            acc[n] = __builtin_amdgcn_mfma_f32_16x16x32_bf16(aw[n][0], bx0, acc[n], 0, 0, 0);
            acc[n] = __builtin_amdgcn_mfma_f32_16x16x32_bf16(aw[n][1], bx1, acc[n], 0, 0, 0);
        }

        if (e < E) {
            if (kb == 0)      idx_out[base + sl] = e;
            else if (kb == 1) idx_in[base + sl] = e;
            const float att = el / dn;
            float* wo = w_out + (size_t)e * D + o0;
#pragma unroll
            for (int n = 0; n < 4; ++n) {
                f32x4 wv;
                wv.x = fmaxf(acc[n][0] + bf2f(psv[n].x) + bf2f(prv[n].x) + bev[n].x, 0.f) * att;
                wv.y = fmaxf(acc[n][1] + bf2f(psv[n].y) + bf2f(prv[n].y) + bev[n].y, 0.f) * att;
                wv.z = fmaxf(acc[n][2] + bf2f(psv[n].z) + bf2f(prv[n].z) + bev[n].z, 0.f) * att;
                wv.w = fmaxf(acc[n][3] + bf2f(psv[n].w) + bf2f(prv[n].w) + bev[n].w, 0.f) * att;
                *(f32x4*)(wo + n * 16) = wv;
            }
        }
        tile = ntile;
    }
}

// ---------------- K5: CSR gather aggregation — 4 rows in flight per wave ----------------
// r13 lesson: agg is REQUEST/latency-bound, not byte-bound. 16 lanes x f32x4 =
// 256B per row, 4 rows per vmem instruction, 2-deep unroll -> 8 independent
// row chains per wave; cross-group shfl_xor reduce at the end.
__global__ __launch_bounds__(256)
void agg_kernel(const float* __restrict__ w_edges,
                const int* __restrict__ idx_out, const int* __restrict__ off_out,
                const int* __restrict__ idx_in, const int* __restrict__ off_in,
                float* __restrict__ out_agg, float* __restrict__ in_agg, int N)
{
    const int lane = threadIdx.x & 63;
    const int wid  = (blockIdx.x * blockDim.x + threadIdx.x) >> 6;
    if (wid >= 2 * N) return;
    const bool is_out = wid < N;
    const int node = is_out ? wid : wid - N;
    const int* __restrict__ idx = is_out ? idx_out : idx_in;
    const int* __restrict__ off = is_out ? off_out : off_in;
    float* __restrict__ dst = is_out ? out_agg : in_agg;

    const int a = off[node], b = off[node + 1];
    const int grp = lane >> 4;        // 0..3: which of 4 concurrent rows
    const int fl  = (lane & 15) * 4;  // f32x4 feature slice

    f32x4 acc  = {0.f, 0.f, 0.f, 0.f};
    f32x4 acc2 = {0.f, 0.f, 0.f, 0.f};
    int j = a + grp;
    for (; j + 4 < b; j += 8) {
        const int i0 = idx[j];
        const int i1 = idx[j + 4];
        acc  += *(const f32x4*)&w_edges[(size_t)i0 * D + fl];
        acc2 += *(const f32x4*)&w_edges[(size_t)i1 * D + fl];
    }
    if (j < b) acc += *(const f32x4*)&w_edges[(size_t)idx[j] * D + fl];
    acc += acc2;

    // reduce across the 4 groups (lanes l, l^16, l^32, l^48)
#pragma unroll
    for (int m = 16; m <= 32; m <<= 1) {
        acc.x += __shfl_xor(acc.x, m, 64);
        acc.y += __shfl_xor(acc.y, m, 64);
        acc.z += __shfl_xor(acc.z, m, 64);
        acc.w += __shfl_xor(acc.w, m, 64);
    }
    if (grp == 0) *(f32x4*)&dst[(size_t)node * D + fl] = acc;
}

// ---------------- K6: node update (3 x K=64 GEMM passes, f32) ----------------
__global__ __launch_bounds__(256)
void node_out_kernel(const float* __restrict__ nodes, const float* __restrict__ oag,
                     const float* __restrict__ iag, const float* __restrict__ Wn,
                     const float* __restrict__ bn, float* __restrict__ out, int N)
{
    __shared__ float sW[64][68];
    __shared__ float sX[64][68];

    const int t = threadIdx.x;
    const int o = t & 63;
    const int k0 = (t >> 6) * 16;
    const int nb = blockIdx.x * 64;
    const int ln = t & 63;
    const int gn = min(nb + ln, N - 1);
    const int o0 = (t & 15) * 4;
    const int rc = (t >> 4) * 4;

    float acc[4][4] = {{0.f,0.f,0.f,0.f},{0.f,0.f,0.f,0.f},{0.f,0.f,0.f,0.f},{0.f,0.f,0.f,0.f}};

#pragma unroll
    for (int g = 0; g < 3; ++g) {
        const float* xbase = (g == 0) ? nodes : ((g == 1) ? oag : iag);
        const float* src = xbase + (size_t)gn * D + k0;
        const f32x4 x0 = *(const f32x4*)(src + 0);
        const f32x4 x1 = *(const f32x4*)(src + 4);
        const f32x4 x2 = *(const f32x4*)(src + 8);
        const f32x4 x3 = *(const f32x4*)(src + 12);
        __syncthreads();
#pragma unroll
        for (int k = 0; k < 16; ++k) {
            sW[k0 + k][o] = Wn[(size_t)o * 192 + g * 64 + k0 + k];
        }
        sX[k0 + 0][ln] = x0.x;  sX[k0 + 1][ln] = x0.y;
        sX[k0 + 2][ln] = x0.z;  sX[k0 + 3][ln] = x0.w;
        sX[k0 + 4][ln] = x1.x;  sX[k0 + 5][ln] = x1.y;
        sX[k0 + 6][ln] = x1.z;  sX[k0 + 7][ln] = x1.w;
        sX[k0 + 8][ln] = x2.x;  sX[k0 + 9][ln] = x2.y;
        sX[k0 + 10][ln] = x2.z; sX[k0 + 11][ln] = x2.w;
        sX[k0 + 12][ln] = x3.x; sX[k0 + 13][ln] = x3.y;
        sX[k0 + 14][ln] = x3.z; sX[k0 + 15][ln] = x3.w;
        __syncthreads();
#pragma unroll 8
        for (int ci = 0; ci < 64; ++ci) {
            const f32x4 xv = *(const f32x4*)&sX[ci][rc];
            const f32x4 wv = *(const f32x4*)&sW[ci][o0];
            acc[0][0] += xv.x * wv.x; acc[0][1] += xv.x * wv.y; acc[0][2] += xv.x * wv.z; acc[0][3] += xv.x * wv.w;
            acc[1][0] += xv.y * wv.x; acc[1][1] += xv.y * wv.y; acc[1][2] += xv.y * wv.z; acc[1][3] += xv.y * wv.w;
            acc[2][0] += xv.z * wv.x; acc[2][1] += xv.z * wv.y; acc[2][2] += xv.z * wv.z; acc[2][3] += xv.z * wv.w;
            acc[3][0] += xv.w * wv.x; acc[3][1] += xv.w * wv.y; acc[3][2] += xv.w * wv.z; acc[3][3] += xv.w * wv.w;
        }
    }

    const f32x4 bnv = *(const f32x4*)&bn[o0];
#pragma unroll
    for (int j = 0; j < 4; ++j) {
        const int n = nb + rc + j;
        if (n < N) {
            f32x4 y;
            y.x = fmaxf(acc[j][0] + bnv.x, 0.f);
            y.y = fmaxf(acc[j][1] + bnv.y, 0.f);
            y.z = fmaxf(acc[j][2] + bnv.z, 0.f);
            y.w = fmaxf(acc[j][3] + bnv.w, 0.f);
            *(f32x4*)&out[(size_t)n * D + o0] = y;
        }
    }
}

extern "C" void kernel_launch(void* const* d_in, const int* in_sizes, int n_in,
                              void* d_out, int out_size, void* d_ws, size_t ws_size,
                              hipStream_t stream) {
    const float* nodes = (const float*)d_in[0];
    const float* edges = (const float*)d_in[1];
    const int*   snd   = (const int*)d_in[2];
    const int*   rcv   = (const int*)d_in[3];
    const float* We    = (const float*)d_in[4];
    const float* be    = (const float*)d_in[5];
    const float* Wn    = (const float*)d_in[6];
    const float* bn    = (const float*)d_in[7];
    const float* Wa    = (const float*)d_in[8];
    const float* ba    = (const float*)d_in[9];

    const int N = in_sizes[0] / D;
    const int E = in_sizes[2];

    float* out_nodes = (float*)d_out;                    // [N, 64]
    float* w_out     = (float*)d_out + (size_t)N * D;    // [E, 64]

    // ws layout (4-byte elems unless noted):
    // zeroed each call: [denom N][deg_out N][deg_in N]
    // [ps N][pr N][off_out N+1][off_in N+1][elog E][idx_out E][idx_in E]
    // [slot_out E][slot_in E][PSb N*64 ushort][PRb N*64 ushort]
    // [out_agg N*64][in_agg N*64]
    char* w = (char*)d_ws;
    float* denom    = (float*)w;                 w += (size_t)N * 4;
    int*   deg_out  = (int*)w;                   w += (size_t)N * 4;
    int*   deg_in   = (int*)w;                   w += (size_t)N * 4;
    float* ps       = (float*)w;                 w += (size_t)N * 4;
    float* pr       = (float*)w;                 w += (size_t)N * 4;
    int*   off_out  = (int*)w;                   w += (size_t)(N + 1) * 4;
    int*   off_in   = (int*)w;                   w += (size_t)(N + 1) * 4;
    float* elog     = (float*)w;                 w += (size_t)E * 4;
    int*   idx_out  = (int*)w;                   w += (size_t)E * 4;
    int*   idx_in   = (int*)w;                   w += (size_t)E * 4;
    int*   slot_out = (int*)w;                   w += (size_t)E * 4;
    int*   slot_in  = (int*)w;                   w += (size_t)E * 4;
    unsigned short* PSb = (unsigned short*)w;    w += (size_t)N * D * 2;
    unsigned short* PRb = (unsigned short*)w;    w += (size_t)N * D * 2;
    float* out_agg  = (float*)w;                 w += (size_t)N * D * 4;
    float* in_agg   = (float*)w;

    hipMemsetAsync(denom, 0, (size_t)3 * N * 4, stream);

    premix_kernel<<<(N + 63) / 64, 256, 0, stream>>>(nodes, We, Wa, PSb, PRb, ps, pr, N);

    edge_logit_kernel<<<1024, 256, 0, stream>>>(snd, rcv, ps, pr, ba, elog,
                                                denom, deg_out, deg_in,
                                                slot_out, slot_in, E);

    scan_kernel<<<2, 1024, 0, stream>>>(deg_out, off_out, deg_in, off_in, N);

    const int nt = (E + 63) / 64;
    const int eblocks = nt < 2048 ? nt : 2048;
    edge_mix_kernel<<<eblocks, 256, 0, stream>>>(edges, snd, rcv, We, be,
                                                 PSb, PRb, elog, denom,
                                                 off_out, off_in, slot_out, slot_in,
                                                 idx_out, idx_in, w_out, E);

    agg_kernel<<<(2 * N + 3) / 4, 256, 0, stream>>>(w_out, idx_out, off_out,
                                                    idx_in, off_in, out_agg, in_agg, N);

    node_out_kernel<<<(N + 63) / 64, 256, 0, stream>>>(nodes, out_agg, in_agg,
                                                       Wn, bn, out_nodes, N);
}